// Round 1
// baseline (152.247 us; speedup 1.0000x reference)
//
#include <hip/hip_runtime.h>

// Problem constants
#define M_ROWS 8192            // B*L = 4*2048
#define N_DIM  1024            // D
#define K3     3072            // 3*D
#define KD     16              // K_DIM

typedef __bf16 bf16x8 __attribute__((ext_vector_type(8)));
typedef float  f32x4  __attribute__((ext_vector_type(4)));

__device__ __forceinline__ unsigned short f2bf(float f) {
  return __builtin_bit_cast(unsigned short, (__bf16)f);
}

__device__ __forceinline__ void async16(const void* g, void* l) {
  __builtin_amdgcn_global_load_lds(
      (const __attribute__((address_space(1))) unsigned int*)g,
      (__attribute__((address_space(3))) unsigned int*)l, 16, 0, 0);
}

// Kernel 1: convert x,y,z (fp32) -> Xb,Yb,Zb (bf16), each 8192x1024 row-major.
__global__ __launch_bounds__(256) void convert_kernel(
    const float4* __restrict__ x, const float4* __restrict__ y, const float4* __restrict__ z,
    ushort4* __restrict__ Xb, ushort4* __restrict__ Yb, ushort4* __restrict__ Zb)
{
  int v = blockIdx.x * 256 + threadIdx.x;          // 0 .. 3*2^21-1 (float4 units)
  int buf = v >> 21;                               // 2^21 float4 per buffer
  int i   = v & ((1 << 21) - 1);
  const float4* src = (buf == 0) ? x : ((buf == 1) ? y : z);
  ushort4*      dst = (buf == 0) ? Xb : ((buf == 1) ? Yb : Zb);
  float4 f = src[i];
  ushort4 o;
  o.x = f2bf(f.x); o.y = f2bf(f.y); o.z = f2bf(f.z); o.w = f2bf(f.w);
  dst[i] = o;
}

// Kernel 2: Wsum[d][c] = bf16( sum_{k<16} W[d*16+k][c] ), 1024x3072 row-major.
__global__ __launch_bounds__(256) void reduce_w_kernel(
    const float* __restrict__ W, ushort4* __restrict__ Wsum)
{
  int g  = blockIdx.x * 256 + threadIdx.x;         // 0 .. 786431 (float4 cols)
  int d  = g / 768;                                // 3072/4 = 768 float4 per row
  int cq = g - d * 768;
  const float4* wrow = (const float4*)(W + (size_t)d * (KD * K3));
  float sx = 0.f, sy = 0.f, sz = 0.f, sw = 0.f;
  #pragma unroll
  for (int k = 0; k < KD; ++k) {
    float4 t = wrow[(size_t)k * (K3 / 4) + cq];
    sx += t.x; sy += t.y; sz += t.z; sw += t.w;
  }
  ushort4 o;
  o.x = f2bf(sx); o.y = f2bf(sy); o.z = f2bf(sz); o.w = f2bf(sw);
  Wsum[g] = o;
}

// Kernel 3: bsum[d] = sum_{k<16} b[d*16+k], fp32.
__global__ __launch_bounds__(256) void reduce_b_kernel(
    const float* __restrict__ b, float* __restrict__ bsum)
{
  int d = blockIdx.x * 256 + threadIdx.x;
  if (d < N_DIM) {
    float s = 0.f;
    #pragma unroll
    for (int k = 0; k < KD; ++k) s += b[d * KD + k];
    bsum[d] = s;
  }
}

// Kernel 4: GEMM C[m,n] = sum_k A[m,k]*Wsum[n,k], fused epilogue
//   out[m,n] = (C + bsum[n]) * x[m,n] * y[m,n]
// 128x128 tile, BK=32, 4 waves (2x2), 16x16x32 bf16 MFMA, global_load_lds(16B).
__global__ __launch_bounds__(256) void gemm_ep_kernel(
    const unsigned short* __restrict__ Xb, const unsigned short* __restrict__ Yb,
    const unsigned short* __restrict__ Zb, const unsigned short* __restrict__ Wsum,
    const float* __restrict__ bsum,
    const float* __restrict__ x, const float* __restrict__ y,
    float* __restrict__ out)
{
  __shared__ unsigned short sA[128 * 32];
  __shared__ unsigned short sB[128 * 32];

  // XCD-aware bijective swizzle: 512 blocks, 8 XCDs, 64 blocks each.
  int bid = blockIdx.x;
  int swz = (bid & 7) * 64 + (bid >> 3);
  int mt = swz >> 3;          // 64 M-tiles
  int nt = swz & 7;           // 8 N-tiles
  int m0 = mt * 128, n0 = nt * 128;

  int tid  = threadIdx.x;
  int lane = tid & 63;
  int wid  = tid >> 6;
  int wr = wid >> 1, wc = wid & 1;   // 2x2 wave grid, each wave 64x64 out

  // staging geometry: 8KB tile = 512 x 16B; 256 threads -> 2 rounds
  int o0 = tid * 16;          // byte offset round 0
  int o1 = o0 + 4096;         // byte offset round 1
  int rowA0 = o0 >> 6;        // 64B per row (32 bf16)
  int rowA1 = o1 >> 6;
  int colh  = (o0 & 63) >> 1; // column in ushort units (same both rounds)

  f32x4 acc[4][4];
  #pragma unroll
  for (int i = 0; i < 4; ++i)
    #pragma unroll
    for (int j = 0; j < 4; ++j)
      acc[i][j] = f32x4{0.f, 0.f, 0.f, 0.f};

  int fr = lane & 15;
  int fk = (lane >> 4) << 3;  // k-offset of this lane's 8 bf16

  for (int kt = 0; kt < K3 / 32; ++kt) {
    int kb = kt >> 5;                          // source buffer: 32 tiles per 1024 K
    const unsigned short* ab = (kb == 0) ? Xb : ((kb == 1) ? Yb : Zb);
    int ck = (kt & 31) << 5;                   // k offset within buffer
    int kw = kt << 5;                          // k offset in Wsum

    async16(ab + (size_t)(m0 + rowA0) * 1024 + ck + colh, (char*)sA + o0);
    async16(ab + (size_t)(m0 + rowA1) * 1024 + ck + colh, (char*)sA + o1);
    async16(Wsum + (size_t)(n0 + rowA0) * K3 + kw + colh, (char*)sB + o0);
    async16(Wsum + (size_t)(n0 + rowA1) * K3 + kw + colh, (char*)sB + o1);
    __syncthreads();   // compiler emits vmcnt(0) drain before barrier

    bf16x8 a[4], b[4];
    #pragma unroll
    for (int i = 0; i < 4; ++i)
      a[i] = *(const bf16x8*)&sA[(wr * 64 + i * 16 + fr) * 32 + fk];
    #pragma unroll
    for (int j = 0; j < 4; ++j)
      b[j] = *(const bf16x8*)&sB[(wc * 64 + j * 16 + fr) * 32 + fk];

    #pragma unroll
    for (int i = 0; i < 4; ++i)
      #pragma unroll
      for (int j = 0; j < 4; ++j)
        acc[i][j] = __builtin_amdgcn_mfma_f32_16x16x32_bf16(a[i], b[j], acc[i][j], 0, 0, 0);

    __syncthreads();   // protect LDS from next iteration's staging
  }

  // Epilogue: C/D layout col = lane&15, row = (lane>>4)*4 + reg  [verified m89/m91]
  int fq = lane >> 4;
  #pragma unroll
  for (int i = 0; i < 4; ++i) {
    #pragma unroll
    for (int j = 0; j < 4; ++j) {
      int n = n0 + wc * 64 + j * 16 + fr;
      float bs = bsum[n];
      #pragma unroll
      for (int r = 0; r < 4; ++r) {
        int m = m0 + wr * 64 + i * 16 + fq * 4 + r;
        size_t idx = (size_t)m * N_DIM + n;
        out[idx] = (acc[i][j][r] + bs) * x[idx] * y[idx];
      }
    }
  }
}

extern "C" void kernel_launch(void* const* d_in, const int* in_sizes, int n_in,
                              void* d_out, int out_size, void* d_ws, size_t ws_size,
                              hipStream_t stream) {
  const float* x = (const float*)d_in[0];
  const float* y = (const float*)d_in[1];
  const float* z = (const float*)d_in[2];
  const float* W = (const float*)d_in[3];
  const float* b = (const float*)d_in[4];
  float* out = (float*)d_out;

  // ws layout (bytes): Xb,Yb,Zb bf16 [8192*1024] each; Wsum bf16 [1024*3072]; bsum f32[1024]
  unsigned short* Xb   = (unsigned short*)d_ws;
  unsigned short* Yb   = Xb + (size_t)M_ROWS * N_DIM;
  unsigned short* Zb   = Yb + (size_t)M_ROWS * N_DIM;
  unsigned short* Wsum = Zb + (size_t)M_ROWS * N_DIM;
  float*          bsum = (float*)(Wsum + (size_t)N_DIM * K3);

  // 1) convert inputs to bf16: 3*8192*1024/4 float4 elements
  convert_kernel<<<24576, 256, 0, stream>>>(
      (const float4*)x, (const float4*)y, (const float4*)z,
      (ushort4*)Xb, (ushort4*)Yb, (ushort4*)Zb);

  // 2) reduce W over k: 1024*768 float4 outputs
  reduce_w_kernel<<<3072, 256, 0, stream>>>(W, (ushort4*)Wsum);

  // 3) reduce bias
  reduce_b_kernel<<<4, 256, 0, stream>>>(b, bsum);

  // 4) GEMM + epilogue: 64 x 8 tiles of 128x128
  gemm_ep_kernel<<<512, 256, 0, stream>>>(Xb, Yb, Zb, Wsum, bsum, x, y, out);
}